// Round 11
// baseline (90.545 us; speedup 1.0000x reference)
//
#include <hip/hip_runtime.h>
#include <math.h>

// Problem constants: gts/preds [4, 8192, 3] fp32; out [4] fp32.
#define BB 4
#define NPTS 8192
#define THREADS 256
#define NQ_TOTAL (2 * BB * NPTS)       // 65536 (dir,b,q) query slots
#define SLICES 8                       // ref-dim split; 16 KB LDS per block
#define RPS (NPTS / SLICES)            // 1024 refs per slice
#define QPB_MIN 256                    // queries per block (4 waves x 64)
#define QGROUPS (NPTS / QPB_MIN)       // 32 query groups per (dir,b)
#define NBLK_MIN (SLICES * 2 * BB * QGROUPS)   // 2048 blocks

typedef __attribute__((ext_vector_type(8)))  short bf16x8;   // MFMA A/B frag
typedef __attribute__((ext_vector_type(16))) float f32x16;   // MFMA C/D frag

// ws layout: minpart only — SLICES * NQ_TOTAL floats (2 MiB).
// MFMA dot(A_row,B_col) = -2 q.r + rr + qq = |q-r|^2 on bf16-rounded points:
//   A slots [-2x,-2y,-2z, 1, 1, qq_hi, qq_lo, 0]
//   B slots [  x,  y,  z, rr_hi, rr_lo, 1, 1, 0]
// rr/qq computed in fp32 FROM THE ROUNDED coords, fed as 2-term bf16 splits.

__device__ __forceinline__ unsigned short f2bf(float f) {   // RNE f32->bf16
    unsigned u = __float_as_uint(f);
    u += 0x7FFF + ((u >> 16) & 1);
    return (unsigned short)(u >> 16);
}
__device__ __forceinline__ float bf2f(unsigned short h) {
    return __uint_as_float(((unsigned)h) << 16);
}

__device__ __forceinline__ uint4 make_bfrag(float x, float y, float z) {
    unsigned short hx = f2bf(x), hy = f2bf(y), hz = f2bf(z);
    float fx = bf2f(hx), fy = bf2f(hy), fz = bf2f(hz);
    float rr = fmaf(fx, fx, fmaf(fy, fy, fz * fz));
    unsigned short hh = f2bf(rr);
    unsigned short hl = f2bf(rr - bf2f(hh));
    uint4 v;
    v.x = (unsigned)hx | ((unsigned)hy << 16);
    v.y = (unsigned)hz | ((unsigned)hh << 16);
    v.z = (unsigned)hl | (0x3F80u << 16);
    v.w = 0x3F80u;
    return v;
}

__device__ __forceinline__ bf16x8 make_afrag(const float* __restrict__ p) {
    unsigned short hx = f2bf(p[0]), hy = f2bf(p[1]), hz = f2bf(p[2]);
    float fx = bf2f(hx), fy = bf2f(hy), fz = bf2f(hz);
    float qq = fmaf(fx, fx, fmaf(fy, fy, fz * fz));
    unsigned short hh = f2bf(qq);
    unsigned short hl = f2bf(qq - bf2f(hh));
    bf16x8 a;
    a[0] = (short)f2bf(-2.0f * fx);      // exact: coords already bf16
    a[1] = (short)f2bf(-2.0f * fy);
    a[2] = (short)f2bf(-2.0f * fz);
    a[3] = (short)0x3F80;
    a[4] = (short)0x3F80;
    a[5] = (short)hh;
    a[6] = (short)hl;
    a[7] = 0;
    return a;
}

// ---------------------------------------------------------------------------
// Kernel 1: fused pack + MFMA min. Each block (4 waves, 256 queries) packs
// its 1024-ref slice straight from raw fp32 into LDS B-frags (4 pts/thread),
// builds its 2 persistent A-frags in registers from raw queries, then scans
// the slice with ds_read_b128 -> 4 MFMAs -> 0.5 v_min3/pair (identical inner
// loop to R10). Kills the pack kernel, one launch gap, and the packed-array
// global round-trip. Block 0 zeroes out[] (merge runs in a later launch).
// D layout (m74/m101): col = lane&31, row = (r&3)+8*(r>>2)+4*(lane>>5).
// ---------------------------------------------------------------------------
__global__ __launch_bounds__(THREADS) void min_kernel(
    const float* __restrict__ gts, const float* __restrict__ preds,
    float* __restrict__ minpart, float* __restrict__ out) {
    __shared__ uint4 sref[RPS];            // 16 KB

    int tid   = threadIdx.x;
    int blk   = blockIdx.x;
    int slice = blk >> 8;                  // / (2*BB*QGROUPS) = /256
    int rem   = blk & 255;
    int dir   = rem >> 7;
    int b     = (rem >> 5) & 3;
    int qg    = rem & 31;                  // query group of 256

    // dir0: queries=preds, refs=gts; dir1: swapped.
    const float* rsrc = (dir ? preds : gts)
                      + ((size_t)b * NPTS + (size_t)slice * RPS) * 3;
    #pragma unroll
    for (int k = 0; k < RPS / THREADS; ++k) {      // 4 points per thread
        int p = k * THREADS + tid;
        sref[p] = make_bfrag(rsrc[3 * p], rsrc[3 * p + 1], rsrc[3 * p + 2]);
    }
    if (blk == 0 && tid < BB) out[tid] = 0.0f;
    __syncthreads();

    int wid  = tid >> 6;
    int lane = tid & 63;
    int l31  = lane & 31;
    int half = lane >> 5;

    // Two persistent A fragments (64 queries per wave); lanes 32-63 zero ->
    // B lanes 32-63 are don't-care -> unconditional full-wave ds_reads.
    const float* qsrc = (dir ? gts : preds)
                      + ((size_t)b * NPTS + (size_t)qg * QPB_MIN
                         + (size_t)wid * 64) * 3;
    bf16x8 a0 = {0, 0, 0, 0, 0, 0, 0, 0};
    bf16x8 a1 = {0, 0, 0, 0, 0, 0, 0, 0};
    if (lane < 32) {
        a0 = make_afrag(qsrc + 3 * l31);
        a1 = make_afrag(qsrc + 3 * (l31 + 32));
    }

    f32x16 zeroc;
    #pragma unroll
    for (int r = 0; r < 16; ++r) zeroc[r] = 0.0f;

    float macc0[16], macc1[16];
    #pragma unroll
    for (int r = 0; r < 16; ++r) { macc0[r] = 3.0e38f; macc1[r] = 3.0e38f; }

    const bf16x8* sp = (const bf16x8*)sref;
    #pragma unroll 2
    for (int t = 0; t < RPS / 64; ++t) {   // 16 iters, 64 refs x 64 queries
        bf16x8 b0 = sp[t * 64 + l31];
        bf16x8 b1 = sp[t * 64 + l31 + 32];
        f32x16 d00 = __builtin_amdgcn_mfma_f32_32x32x16_bf16(a0, b0, zeroc, 0, 0, 0);
        f32x16 d01 = __builtin_amdgcn_mfma_f32_32x32x16_bf16(a0, b1, zeroc, 0, 0, 0);
        #pragma unroll
        for (int r = 0; r < 16; ++r)
            macc0[r] = fminf(fminf(d00[r], d01[r]), macc0[r]);   // v_min3_f32
        f32x16 d10 = __builtin_amdgcn_mfma_f32_32x32x16_bf16(a1, b0, zeroc, 0, 0, 0);
        f32x16 d11 = __builtin_amdgcn_mfma_f32_32x32x16_bf16(a1, b1, zeroc, 0, 0, 0);
        #pragma unroll
        for (int r = 0; r < 16; ++r)
            macc1[r] = fminf(fminf(d10[r], d11[r]), macc1[r]);
    }

    // Min across the 32 cols (lanes within each half), per row register.
    #pragma unroll
    for (int s = 1; s <= 16; s <<= 1) {
        #pragma unroll
        for (int r = 0; r < 16; ++r) {
            macc0[r] = fminf(macc0[r], __shfl_xor(macc0[r], s, 64));
            macc1[r] = fminf(macc1[r], __shfl_xor(macc1[r], s, 64));
        }
    }

    // Lane r of each half writes row(r, half), for both query tiles.
    float* mp = minpart + (size_t)slice * NQ_TOTAL
              + (size_t)(dir * BB + b) * NPTS + (size_t)qg * QPB_MIN
              + (size_t)wid * 64;
    #pragma unroll
    for (int r = 0; r < 16; ++r) {
        int row = (r & 3) + 8 * (r >> 2) + 4 * half;
        if (l31 == r) {
            mp[row]      = macc0[r];
            mp[row + 32] = macc1[r];
        }
    }
}

// ---------------------------------------------------------------------------
// Kernel 2: merge slices, sqrt, block-reduce, atomicAdd into out[b].
// ---------------------------------------------------------------------------
__global__ __launch_bounds__(THREADS) void merge_kernel(
    const float* __restrict__ minpart, float* __restrict__ out) {
    int q = blockIdx.x * THREADS + threadIdx.x;    // 0 .. NQ_TOTAL-1
    float m = minpart[q];
    #pragma unroll
    for (int s = 1; s < SLICES; ++s)
        m = fminf(m, minpart[(size_t)s * NQ_TOTAL + q]);
    float d = sqrtf(fmaxf(m, 0.0f));
    int b = (q >> 13) & 3;                         // uniform within a block

    float sum = d;
    #pragma unroll
    for (int off = 32; off > 0; off >>= 1)
        sum += __shfl_down(sum, off, 64);

    __shared__ float wsum[THREADS / 64];
    int lane = threadIdx.x & 63;
    int wid  = threadIdx.x >> 6;
    if (lane == 0) wsum[wid] = sum;
    __syncthreads();
    if (threadIdx.x == 0)
        atomicAdd(out + b, wsum[0] + wsum[1] + wsum[2] + wsum[3]);
}

extern "C" void kernel_launch(void* const* d_in, const int* in_sizes, int n_in,
                              void* d_out, int out_size, void* d_ws, size_t ws_size,
                              hipStream_t stream) {
    const float* gts   = (const float*)d_in[0];
    const float* preds = (const float*)d_in[1];
    float* out = (float*)d_out;
    float* minpart = (float*)d_ws;                 // 2 MiB

    min_kernel<<<NBLK_MIN, THREADS, 0, stream>>>(gts, preds, minpart, out);
    merge_kernel<<<NQ_TOTAL / THREADS, THREADS, 0, stream>>>(minpart, out);
}